// Round 1
// baseline (1531.449 us; speedup 1.0000x reference)
//
#include <hip/hip_runtime.h>
#include <hip/hip_bf16.h>

typedef unsigned short ushort_t;
typedef __attribute__((ext_vector_type(8))) __bf16 bf16x8;
typedef __attribute__((ext_vector_type(4))) float f32x4;

#define B_ 8
#define T_ 340
#define M_ 32
#define H_ 512
#define NH_ 8
#define DH_ 64
#define INFO_ 1020
#define L_ 1084
#define LP_ 1088
#define MROWS 8672
#define MPAD 8704
#define HMLP 2048

__device__ __forceinline__ ushort_t f2bf(float f) {
  unsigned u = __builtin_bit_cast(unsigned, f);
  unsigned r = (u + 0x7fffu + ((u >> 16) & 1u)) >> 16;
  return (ushort_t)r;
}

// ---------------- zero pads (Q/K l-pads, Vt l-pads, Ob row-pads) ----------------
__global__ __launch_bounds__(256) void zero_pads_kernel(ushort_t* Qb, ushort_t* Kb,
                                                        ushort_t* Vt, ushort_t* Ob) {
  int idx = blockIdx.x * 256 + threadIdx.x;
  if (idx < 16384) {
    int bh = idx >> 8;
    int rest = idx & 255;
    int l = L_ + (rest >> 6);
    int d = rest & 63;
    size_t o = ((size_t)bh * LP_ + l) * DH_ + d;
    Qb[o] = 0;
    Kb[o] = 0;
    Vt[((size_t)bh * DH_ + d) * LP_ + l] = 0;
  } else if (idx < 32768) {
    int j = idx - 16384;
    Ob[(size_t)MROWS * H_ + j] = 0;
  }
}

// ---------------- f32 -> bf16 convert ----------------
__global__ __launch_bounds__(256) void cvt_kernel(const float* __restrict__ src,
                                                  ushort_t* __restrict__ dst, int n) {
  int i = blockIdx.x * 256 + threadIdx.x;
  int stride = gridDim.x * 256;
  for (; i < n; i += stride) dst[i] = f2bf(src[i]);
}

// ---------------- embedding + initial LN ----------------
__global__ __launch_bounds__(256) void embed_ln_kernel(
    const float* __restrict__ returns, const float* __restrict__ actions,
    const float* __restrict__ t_table, const float* __restrict__ s_table,
    const float* __restrict__ Wr, const float* __restrict__ br,
    const float* __restrict__ Wa, const float* __restrict__ ba,
    const float* __restrict__ g, const float* __restrict__ be,
    const float* __restrict__ read_mem, const float* __restrict__ mem_tok,
    const int* __restrict__ states, const int* __restrict__ timestep,
    float* __restrict__ X, ushort_t* __restrict__ Xb) {
  const int row = blockIdx.x;
  const int tid = threadIdx.x;
  if (row >= MROWS) {
    Xb[(size_t)row * H_ + tid] = 0;
    Xb[(size_t)row * H_ + tid + 256] = 0;
    return;
  }
  const int b = row / L_, l = row - b * L_;
  float v[2];
#pragma unroll
  for (int s2 = 0; s2 < 2; s2++) {
    int hh = tid + s2 * 256;
    float val;
    if (l < M_) {
      val = read_mem[(size_t)l * H_ + hh];
    } else if (l >= M_ + INFO_) {
      val = mem_tok[(size_t)(l - M_ - INFO_) * H_ + hh];
    } else {
      int ii = l - M_;
      int t = ii / 3, c = ii - t * 3;
      int bt = b * T_ + t;
      if (c == 1) {
        val = s_table[(size_t)states[bt] * H_ + hh];
      } else {
        float te = t_table[(size_t)timestep[bt] * H_ + hh];
        val = (c == 0 ? returns[bt] * Wr[hh] + br[hh] : actions[bt] * Wa[hh] + ba[hh]) + te;
      }
    }
    v[s2] = val;
  }
  float sum = v[0] + v[1], sq = v[0] * v[0] + v[1] * v[1];
  __shared__ float sa[4], sb[4];
#pragma unroll
  for (int o = 1; o < 64; o <<= 1) {
    sum += __shfl_xor(sum, o);
    sq += __shfl_xor(sq, o);
  }
  int wv = tid >> 6, lane = tid & 63;
  if (lane == 0) { sa[wv] = sum; sb[wv] = sq; }
  __syncthreads();
  sum = sa[0] + sa[1] + sa[2] + sa[3];
  sq = sb[0] + sb[1] + sb[2] + sb[3];
  float mu = sum * (1.0f / H_);
  float var = sq * (1.0f / H_) - mu * mu;
  float rstd = rsqrtf(var + 1e-5f);
#pragma unroll
  for (int s2 = 0; s2 < 2; s2++) {
    int hh = tid + s2 * 256;
    float y = (v[s2] - mu) * rstd * g[hh] + be[hh];
    X[(size_t)row * H_ + hh] = y;
    Xb[(size_t)row * H_ + hh] = f2bf(y);
  }
}

// ---------------- LN over residual stream (in place) ----------------
__global__ __launch_bounds__(256) void ln_kernel(float* __restrict__ X,
                                                 const float* __restrict__ g,
                                                 const float* __restrict__ be,
                                                 ushort_t* __restrict__ Xb) {
  const int row = blockIdx.x;
  const int tid = threadIdx.x;
  if (row >= MROWS) {
    Xb[(size_t)row * H_ + tid] = 0;
    Xb[(size_t)row * H_ + tid + 256] = 0;
    return;
  }
  float v0 = X[(size_t)row * H_ + tid];
  float v1 = X[(size_t)row * H_ + tid + 256];
  float sum = v0 + v1, sq = v0 * v0 + v1 * v1;
  __shared__ float sa[4], sb[4];
#pragma unroll
  for (int o = 1; o < 64; o <<= 1) {
    sum += __shfl_xor(sum, o);
    sq += __shfl_xor(sq, o);
  }
  int wv = tid >> 6, lane = tid & 63;
  if (lane == 0) { sa[wv] = sum; sb[wv] = sq; }
  __syncthreads();
  sum = sa[0] + sa[1] + sa[2] + sa[3];
  sq = sb[0] + sb[1] + sb[2] + sb[3];
  float mu = sum * (1.0f / H_);
  float var = sq * (1.0f / H_) - mu * mu;
  float rstd = rsqrtf(var + 1e-5f);
  float y0 = (v0 - mu) * rstd * g[tid] + be[tid];
  float y1 = (v1 - mu) * rstd * g[tid + 256] + be[tid + 256];
  X[(size_t)row * H_ + tid] = y0;
  X[(size_t)row * H_ + tid + 256] = y1;
  Xb[(size_t)row * H_ + tid] = f2bf(y0);
  Xb[(size_t)row * H_ + tid + 256] = f2bf(y1);
}

// ---------------- GEMM: C[m,n] = sum_k A[m,k]*W[n,k] + bias[n], with epilogues ------
// MODE 0: scatter bf16 to (b,h,l,d)   [Q,K]
// MODE 1: scatter bf16 to (b,h,d,l)   [V transposed]
// MODE 2: f32 X[m,n] = X[m,n] + acc + bias (residual add, N=512)
// MODE 3: bf16 Hm[m,n] = gelu(acc + bias) (N=2048)
template <int MODE>
__global__ __launch_bounds__(256) void gemm_kernel(const ushort_t* __restrict__ A,
                                                   const ushort_t* __restrict__ W,
                                                   const float* __restrict__ bias,
                                                   void* __restrict__ outp,
                                                   float* __restrict__ resid, int Ntiles,
                                                   int K) {
  __shared__ ushort_t As[128 * 32];
  __shared__ ushort_t Bs[128 * 32];
  const int tid = threadIdx.x;
  const int bx = blockIdx.x % Ntiles, by = blockIdx.x / Ntiles;
  const int m0 = by * 128, n0 = bx * 128;
  const int lane = tid & 63, wv = tid >> 6;
  const int wr = wv >> 1, wc = wv & 1;
  f32x4 acc[4][4];
#pragma unroll
  for (int i = 0; i < 4; i++)
#pragma unroll
    for (int j = 0; j < 4; j++) acc[i][j] = (f32x4){0.f, 0.f, 0.f, 0.f};

  const int e0 = tid, e1 = tid + 256;
  const ushort_t* Arow0 = A + (size_t)(m0 + (e0 >> 2)) * K + (e0 & 3) * 8;
  const ushort_t* Arow1 = A + (size_t)(m0 + (e1 >> 2)) * K + (e1 & 3) * 8;
  const ushort_t* Wrow0 = W + (size_t)(n0 + (e0 >> 2)) * K + (e0 & 3) * 8;
  const ushort_t* Wrow1 = W + (size_t)(n0 + (e1 >> 2)) * K + (e1 & 3) * 8;

  for (int k0 = 0; k0 < K; k0 += 32) {
    bf16x8 a0 = *(const bf16x8*)(Arow0 + k0);
    bf16x8 a1 = *(const bf16x8*)(Arow1 + k0);
    bf16x8 w0 = *(const bf16x8*)(Wrow0 + k0);
    bf16x8 w1 = *(const bf16x8*)(Wrow1 + k0);
    *(bf16x8*)&As[e0 * 8] = a0;
    *(bf16x8*)&As[e1 * 8] = a1;
    *(bf16x8*)&Bs[e0 * 8] = w0;
    *(bf16x8*)&Bs[e1 * 8] = w1;
    __syncthreads();
    bf16x8 af[4], bfr[4];
#pragma unroll
    for (int mi = 0; mi < 4; mi++)
      af[mi] = *(const bf16x8*)&As[(wr * 64 + mi * 16 + (lane & 15)) * 32 + (lane >> 4) * 8];
#pragma unroll
    for (int ni = 0; ni < 4; ni++)
      bfr[ni] = *(const bf16x8*)&Bs[(wc * 64 + ni * 16 + (lane & 15)) * 32 + (lane >> 4) * 8];
#pragma unroll
    for (int mi = 0; mi < 4; mi++)
#pragma unroll
      for (int ni = 0; ni < 4; ni++)
        acc[mi][ni] = __builtin_amdgcn_mfma_f32_16x16x32_bf16(af[mi], bfr[ni], acc[mi][ni], 0, 0, 0);
    __syncthreads();
  }

#pragma unroll
  for (int mi = 0; mi < 4; mi++) {
#pragma unroll
    for (int ni = 0; ni < 4; ni++) {
#pragma unroll
      for (int r = 0; r < 4; r++) {
        int m = m0 + wr * 64 + mi * 16 + ((lane >> 4) << 2) + r;
        int n = n0 + wc * 64 + ni * 16 + (lane & 15);
        float val = acc[mi][ni][r] + bias[n];
        if (MODE == 0 || MODE == 1) {
          if (m < MROWS) {
            int b = m / L_;
            int l = m - b * L_;
            int h = n >> 6, d = n & 63;
            ushort_t* o = (ushort_t*)outp;
            if (MODE == 0)
              o[(((size_t)(b * NH_ + h)) * LP_ + l) * DH_ + d] = f2bf(val);
            else
              o[(((size_t)(b * NH_ + h)) * DH_ + d) * LP_ + l] = f2bf(val);
          }
        } else if (MODE == 2) {
          if (m < MROWS) {
            float* o = (float*)outp;
            size_t off = (size_t)m * H_ + n;
            o[off] = resid[off] + val;
          }
        } else {
          float ge = 0.5f * val * (1.0f + erff(val * 0.70710678f));
          ((ushort_t*)outp)[(size_t)m * HMLP + n] = f2bf(ge);
        }
      }
    }
  }
}

// ---------------- flash attention (1 wave per 16 q-rows) ----------------
__global__ __launch_bounds__(256) void attn_kernel(const ushort_t* __restrict__ Qb,
                                                   const ushort_t* __restrict__ Kb,
                                                   const ushort_t* __restrict__ Vt,
                                                   ushort_t* __restrict__ Ob) {
  __shared__ ushort_t Plds[4][16 * 32];
  const int tid = threadIdx.x;
  const int lane = tid & 63, wv = tid >> 6;
  const int bh = blockIdx.x / 17;
  const int qg = blockIdx.x % 17;
  const int b = bh >> 3, h = bh & 7;
  const int i0 = (qg * 4 + wv) * 16;
  const ushort_t* Qp = Qb + (size_t)bh * LP_ * DH_;
  const ushort_t* Kp = Kb + (size_t)bh * LP_ * DH_;
  const ushort_t* Vp = Vt + (size_t)bh * DH_ * LP_;
  const int lr = lane & 15, lg = lane >> 4;

  bf16x8 aq0 = *(const bf16x8*)(Qp + (size_t)(i0 + lr) * DH_ + lg * 8);
  bf16x8 aq1 = *(const bf16x8*)(Qp + (size_t)(i0 + lr) * DH_ + 32 + lg * 8);

  f32x4 Oa[4];
#pragma unroll
  for (int n2 = 0; n2 < 4; n2++) Oa[n2] = (f32x4){0.f, 0.f, 0.f, 0.f};
  float mrun[4] = {-1e30f, -1e30f, -1e30f, -1e30f};
  float lrun[4] = {0.f, 0.f, 0.f, 0.f};

  const int imax = i0 + 15;
  const int kmax = (imax >= M_ + INFO_) ? L_ : ((imax < M_) ? M_ : (imax + 1));
  const int kend = (kmax + 31) & ~31;

  for (int j0 = 0; j0 < kend; j0 += 32) {
    f32x4 s[2];
#pragma unroll
    for (int t2 = 0; t2 < 2; t2++) {
      int jb = j0 + t2 * 16;
      bf16x8 bk0 = *(const bf16x8*)(Kp + (size_t)(jb + lr) * DH_ + lg * 8);
      bf16x8 bk1 = *(const bf16x8*)(Kp + (size_t)(jb + lr) * DH_ + 32 + lg * 8);
      f32x4 z = (f32x4){0.f, 0.f, 0.f, 0.f};
      z = __builtin_amdgcn_mfma_f32_16x16x32_bf16(aq0, bk0, z, 0, 0, 0);
      z = __builtin_amdgcn_mfma_f32_16x16x32_bf16(aq1, bk1, z, 0, 0, 0);
      s[t2] = z;
    }
#pragma unroll
    for (int t2 = 0; t2 < 2; t2++)
#pragma unroll
      for (int r = 0; r < 4; r++) {
        int i = i0 + lg * 4 + r;
        int j = j0 + t2 * 16 + lr;
        bool ok = (j < L_) && ((j < M_) || (i >= M_ + INFO_) || (j <= i));
        s[t2][r] = ok ? s[t2][r] * 0.125f : -1e30f;
      }
    float pr[2][4];
#pragma unroll
    for (int r = 0; r < 4; r++) {
      float mx = fmaxf(s[0][r], s[1][r]);
#pragma unroll
      for (int o2 = 1; o2 < 16; o2 <<= 1) mx = fmaxf(mx, __shfl_xor(mx, o2));
      float mn = fmaxf(mrun[r], mx);
      float fs = __expf(mrun[r] - mn);
      mrun[r] = mn;
      float p0 = __expf(s[0][r] - mn);
      float p1 = __expf(s[1][r] - mn);
      pr[0][r] = p0;
      pr[1][r] = p1;
      float ps = p0 + p1;
#pragma unroll
      for (int o2 = 1; o2 < 16; o2 <<= 1) ps += __shfl_xor(ps, o2);
      lrun[r] = lrun[r] * fs + ps;
#pragma unroll
      for (int n2 = 0; n2 < 4; n2++) Oa[n2][r] *= fs;
    }
    ushort_t* pl = Plds[wv];
#pragma unroll
    for (int t2 = 0; t2 < 2; t2++)
#pragma unroll
      for (int r = 0; r < 4; r++) pl[(lg * 4 + r) * 32 + t2 * 16 + lr] = f2bf(pr[t2][r]);
    bf16x8 pa = *(const bf16x8*)&pl[lr * 32 + lg * 8];
#pragma unroll
    for (int n2 = 0; n2 < 4; n2++) {
      bf16x8 bv = *(const bf16x8*)(Vp + (size_t)(n2 * 16 + lr) * LP_ + j0 + lg * 8);
      Oa[n2] = __builtin_amdgcn_mfma_f32_16x16x32_bf16(pa, bv, Oa[n2], 0, 0, 0);
    }
  }
#pragma unroll
  for (int r = 0; r < 4; r++) {
    int i = i0 + lg * 4 + r;
    if (i < L_) {
      float inv = 1.0f / lrun[r];
      size_t rowb = ((size_t)(b * L_ + i)) * H_ + h * DH_;
#pragma unroll
      for (int n2 = 0; n2 < 4; n2++) Ob[rowb + n2 * 16 + lr] = f2bf(Oa[n2][r] * inv);
    }
  }
}

// ---------------- heads ----------------
__global__ __launch_bounds__(64) void logits_kernel(const float* __restrict__ X,
                                                    const float* __restrict__ Wp,
                                                    const float* __restrict__ bp,
                                                    float* __restrict__ out) {
  const int bt = blockIdx.x;
  const int b = bt / T_, t = bt - b * T_;
  const int lane = threadIdx.x;
  const float* xr = X + ((size_t)(b * L_ + M_ + 3 * t + 1)) * H_ + lane * 8;
  float x0[8];
#pragma unroll
  for (int i = 0; i < 8; i++) x0[i] = xr[i];
#pragma unroll
  for (int a = 0; a < 4; a++) {
    const float* wr2 = Wp + (size_t)a * H_ + lane * 8;
    float p = 0.f;
#pragma unroll
    for (int i = 0; i < 8; i++) p += x0[i] * wr2[i];
#pragma unroll
    for (int o = 1; o < 64; o <<= 1) p += __shfl_xor(p, o);
    if (lane == 0) out[(size_t)bt * 4 + a] = p + bp[a];
  }
}

__global__ __launch_bounds__(256) void memout_kernel(const float* __restrict__ X,
                                                     float* __restrict__ out) {
  int idx = blockIdx.x * 256 + threadIdx.x;
  if (idx < B_ * M_ * H_) {
    int b = idx >> 14;
    int rest = idx & 16383;
    int r = rest >> 9;
    int hh = rest & 511;
    out[idx] = X[((size_t)(b * L_ + M_ + INFO_ + r)) * H_ + hh];
  }
}

// ---------------- launcher ----------------
extern "C" void kernel_launch(void* const* d_in, const int* in_sizes, int n_in, void* d_out,
                              int out_size, void* d_ws, size_t ws_size, hipStream_t stream) {
  const float* returns = (const float*)d_in[0];
  const float* actions = (const float*)d_in[1];
  const float* t_table = (const float*)d_in[2];
  const float* s_table = (const float*)d_in[3];
  const float* Wr = (const float*)d_in[4];
  const float* br = (const float*)d_in[5];
  const float* Wa = (const float*)d_in[6];
  const float* ba = (const float*)d_in[7];
  const float* ln_e_g = (const float*)d_in[8];
  const float* ln_e_b = (const float*)d_in[9];
  const float* read_mem = (const float*)d_in[10];
  const float* mem_tok = (const float*)d_in[11];
  const float* Wq = (const float*)d_in[12];
  const float* bq = (const float*)d_in[13];
  const float* Wk = (const float*)d_in[14];
  const float* bk = (const float*)d_in[15];
  const float* Wv = (const float*)d_in[16];
  const float* bv = (const float*)d_in[17];
  const float* Wo = (const float*)d_in[18];
  const float* bo = (const float*)d_in[19];
  const float* W1 = (const float*)d_in[20];
  const float* b1 = (const float*)d_in[21];
  const float* W2 = (const float*)d_in[22];
  const float* b2 = (const float*)d_in[23];
  const float* g1 = (const float*)d_in[24];
  const float* be1 = (const float*)d_in[25];
  const float* g2 = (const float*)d_in[26];
  const float* be2 = (const float*)d_in[27];
  const float* Wp = (const float*)d_in[28];
  const float* bp = (const float*)d_in[29];
  const int* states = (const int*)d_in[30];
  const int* timestep = (const int*)d_in[31];

  char* ws = (char*)d_ws;
  size_t off = 0;
  auto alloc = [&](size_t bytes) -> char* {
    char* p = ws + off;
    off += (bytes + 255) & ~(size_t)255;
    return p;
  };
  float* X = (float*)alloc((size_t)MPAD * H_ * 4);
  ushort_t* Xb = (ushort_t*)alloc((size_t)MPAD * H_ * 2);
  ushort_t* Qb = (ushort_t*)alloc((size_t)B_ * NH_ * LP_ * DH_ * 2);
  ushort_t* Kb2 = (ushort_t*)alloc((size_t)B_ * NH_ * LP_ * DH_ * 2);
  ushort_t* Vt = (ushort_t*)alloc((size_t)B_ * NH_ * DH_ * LP_ * 2);
  ushort_t* Ob = (ushort_t*)alloc((size_t)MPAD * H_ * 2);
  ushort_t* Hm = (ushort_t*)alloc((size_t)MPAD * HMLP * 2);
  ushort_t* Wqb = (ushort_t*)alloc((size_t)4 * 512 * 512 * 2);
  ushort_t* Wkb = (ushort_t*)alloc((size_t)4 * 512 * 512 * 2);
  ushort_t* Wvb = (ushort_t*)alloc((size_t)4 * 512 * 512 * 2);
  ushort_t* Wob = (ushort_t*)alloc((size_t)4 * 512 * 512 * 2);
  ushort_t* W1b = (ushort_t*)alloc((size_t)4 * 2048 * 512 * 2);
  ushort_t* W2b = (ushort_t*)alloc((size_t)4 * 512 * 2048 * 2);

  zero_pads_kernel<<<128, 256, 0, stream>>>(Qb, Kb2, Vt, Ob);
  cvt_kernel<<<512, 256, 0, stream>>>(Wq, Wqb, 4 * 512 * 512);
  cvt_kernel<<<512, 256, 0, stream>>>(Wk, Wkb, 4 * 512 * 512);
  cvt_kernel<<<512, 256, 0, stream>>>(Wv, Wvb, 4 * 512 * 512);
  cvt_kernel<<<512, 256, 0, stream>>>(Wo, Wob, 4 * 512 * 512);
  cvt_kernel<<<512, 256, 0, stream>>>(W1, W1b, 4 * 2048 * 512);
  cvt_kernel<<<512, 256, 0, stream>>>(W2, W2b, 4 * 512 * 2048);

  embed_ln_kernel<<<MPAD, 256, 0, stream>>>(returns, actions, t_table, s_table, Wr, br, Wa,
                                            ba, ln_e_g, ln_e_b, read_mem, mem_tok, states,
                                            timestep, X, Xb);

  for (int nb = 0; nb < 4; ++nb) {
    const size_t wo512 = (size_t)nb * 512 * 512;
    const size_t wo1 = (size_t)nb * 2048 * 512;
    gemm_kernel<0><<<68 * 4, 256, 0, stream>>>(Xb, Wqb + wo512, bq + nb * 512, Qb, nullptr, 4, 512);
    gemm_kernel<0><<<68 * 4, 256, 0, stream>>>(Xb, Wkb + wo512, bk + nb * 512, Kb2, nullptr, 4, 512);
    gemm_kernel<1><<<68 * 4, 256, 0, stream>>>(Xb, Wvb + wo512, bv + nb * 512, Vt, nullptr, 4, 512);
    attn_kernel<<<64 * 17, 256, 0, stream>>>(Qb, Kb2, Vt, Ob);
    gemm_kernel<2><<<68 * 4, 256, 0, stream>>>(Ob, Wob + wo512, bo + nb * 512, X, X, 4, 512);
    ln_kernel<<<MPAD, 256, 0, stream>>>(X, g1 + nb * 512, be1 + nb * 512, Xb);
    gemm_kernel<3><<<68 * 16, 256, 0, stream>>>(Xb, W1b + wo1, b1 + nb * 2048, Hm, nullptr, 16, 512);
    gemm_kernel<2><<<68 * 4, 256, 0, stream>>>(Hm, W2b + wo1, b2 + nb * 512, X, X, 4, 2048);
    ln_kernel<<<MPAD, 256, 0, stream>>>(X, g2 + nb * 512, be2 + nb * 512, Xb);
  }

  logits_kernel<<<B_ * T_, 64, 0, stream>>>(X, Wp, bp, (float*)d_out);
  memout_kernel<<<512, 256, 0, stream>>>(X, (float*)d_out + (size_t)B_ * T_ * 4);
}

// Round 2
// 1186.769 us; speedup vs baseline: 1.2904x; 1.2904x over previous
//
#include <hip/hip_runtime.h>
#include <hip/hip_bf16.h>

typedef unsigned short ushort_t;
typedef __attribute__((ext_vector_type(8))) __bf16 bf16x8;
typedef __attribute__((ext_vector_type(4))) float f32x4;
typedef __attribute__((ext_vector_type(16))) float f32x16;
typedef __attribute__((ext_vector_type(2))) unsigned u32x2;
typedef __attribute__((ext_vector_type(4))) unsigned u32x4;

#define B_ 8
#define T_ 340
#define M_ 32
#define H_ 512
#define NH_ 8
#define DH_ 64
#define INFO_ 1020
#define L_ 1084
#define LP_ 1088
#define MROWS 8672
#define MPAD 8704
#define HMLP 2048

__device__ __forceinline__ ushort_t f2bf(float f) {
  unsigned u = __builtin_bit_cast(unsigned, f);
  unsigned r = (u + 0x7fffu + ((u >> 16) & 1u)) >> 16;
  return (ushort_t)r;
}

__device__ __forceinline__ unsigned cvtpk_bf16(float lo, float hi) {
  unsigned r;
  asm volatile("v_cvt_pk_bf16_f32 %0, %1, %2" : "=v"(r) : "v"(lo), "v"(hi));
  return r;
}

__device__ __forceinline__ void gload16(const ushort_t* g, ushort_t* l) {
  __builtin_amdgcn_global_load_lds((const __attribute__((address_space(1))) unsigned*)g,
                                   (__attribute__((address_space(3))) unsigned*)l, 16, 0, 0);
}

// ---------------- zero pads (Q/K l-pads, Vt l-pads, Ob row-pads) ----------------
__global__ __launch_bounds__(256) void zero_pads_kernel(ushort_t* Qb, ushort_t* Kb,
                                                        ushort_t* Vt, ushort_t* Ob) {
  int idx = blockIdx.x * 256 + threadIdx.x;
  if (idx < 16384) {
    int bh = idx >> 8;
    int rest = idx & 255;
    int l = L_ + (rest >> 6);
    int d = rest & 63;
    size_t o = ((size_t)bh * LP_ + l) * DH_ + d;
    Qb[o] = 0;
    Kb[o] = 0;
    Vt[((size_t)bh * DH_ + d) * LP_ + l] = 0;
  } else if (idx < 32768) {
    int j = idx - 16384;
    Ob[(size_t)MROWS * H_ + j] = 0;
  }
}

// ---------------- f32 -> bf16 convert ----------------
__global__ __launch_bounds__(256) void cvt_kernel(const float* __restrict__ src,
                                                  ushort_t* __restrict__ dst, int n) {
  int i = blockIdx.x * 256 + threadIdx.x;
  int stride = gridDim.x * 256;
  for (; i < n; i += stride) dst[i] = f2bf(src[i]);
}

// ---------------- Wq/Wk/Wv -> concatenated bf16 [nb][1536][512] ----------------
__global__ __launch_bounds__(256) void cvtqkv_kernel(const float* __restrict__ q,
                                                     const float* __restrict__ k,
                                                     const float* __restrict__ v,
                                                     ushort_t* __restrict__ dst) {
  int i = blockIdx.x * 256 + threadIdx.x;
  if (i >= 4 * 512 * 512) return;
  int nb = i >> 18;
  int rem = i & 262143;
  size_t base = (size_t)nb * 786432 + rem;
  dst[base] = f2bf(q[i]);
  dst[base + 262144] = f2bf(k[i]);
  dst[base + 524288] = f2bf(v[i]);
}

__global__ __launch_bounds__(256) void biascat_kernel(const float* __restrict__ bq,
                                                      const float* __restrict__ bk,
                                                      const float* __restrict__ bv,
                                                      float* __restrict__ dst) {
  int i = blockIdx.x * 256 + threadIdx.x;
  if (i < 2048) {
    int nb = i >> 9, r = i & 511;
    float* d = dst + nb * 1536;
    d[r] = bq[i];
    d[512 + r] = bk[i];
    d[1024 + r] = bv[i];
  }
}

// ---------------- embedding + initial LN ----------------
__global__ __launch_bounds__(256) void embed_ln_kernel(
    const float* __restrict__ returns, const float* __restrict__ actions,
    const float* __restrict__ t_table, const float* __restrict__ s_table,
    const float* __restrict__ Wr, const float* __restrict__ br,
    const float* __restrict__ Wa, const float* __restrict__ ba,
    const float* __restrict__ g, const float* __restrict__ be,
    const float* __restrict__ read_mem, const float* __restrict__ mem_tok,
    const int* __restrict__ states, const int* __restrict__ timestep,
    float* __restrict__ X, ushort_t* __restrict__ Xb) {
  const int row = blockIdx.x;
  const int tid = threadIdx.x;
  if (row >= MROWS) {
    Xb[(size_t)row * H_ + tid] = 0;
    Xb[(size_t)row * H_ + tid + 256] = 0;
    return;
  }
  const int b = row / L_, l = row - b * L_;
  float v[2];
#pragma unroll
  for (int s2 = 0; s2 < 2; s2++) {
    int hh = tid + s2 * 256;
    float val;
    if (l < M_) {
      val = read_mem[(size_t)l * H_ + hh];
    } else if (l >= M_ + INFO_) {
      val = mem_tok[(size_t)(l - M_ - INFO_) * H_ + hh];
    } else {
      int ii = l - M_;
      int t = ii / 3, c = ii - t * 3;
      int bt = b * T_ + t;
      if (c == 1) {
        val = s_table[(size_t)states[bt] * H_ + hh];
      } else {
        float te = t_table[(size_t)timestep[bt] * H_ + hh];
        val = (c == 0 ? returns[bt] * Wr[hh] + br[hh] : actions[bt] * Wa[hh] + ba[hh]) + te;
      }
    }
    v[s2] = val;
  }
  float sum = v[0] + v[1], sq = v[0] * v[0] + v[1] * v[1];
  __shared__ float sa[4], sb[4];
#pragma unroll
  for (int o = 1; o < 64; o <<= 1) {
    sum += __shfl_xor(sum, o);
    sq += __shfl_xor(sq, o);
  }
  int wv = tid >> 6, lane = tid & 63;
  if (lane == 0) { sa[wv] = sum; sb[wv] = sq; }
  __syncthreads();
  sum = sa[0] + sa[1] + sa[2] + sa[3];
  sq = sb[0] + sb[1] + sb[2] + sb[3];
  float mu = sum * (1.0f / H_);
  float var = sq * (1.0f / H_) - mu * mu;
  float rstd = rsqrtf(var + 1e-5f);
#pragma unroll
  for (int s2 = 0; s2 < 2; s2++) {
    int hh = tid + s2 * 256;
    float y = (v[s2] - mu) * rstd * g[hh] + be[hh];
    X[(size_t)row * H_ + hh] = y;
    Xb[(size_t)row * H_ + hh] = f2bf(y);
  }
}

// ---------------- LN over residual stream (in place) ----------------
__global__ __launch_bounds__(256) void ln_kernel(float* __restrict__ X,
                                                 const float* __restrict__ g,
                                                 const float* __restrict__ be,
                                                 ushort_t* __restrict__ Xb) {
  const int row = blockIdx.x;
  const int tid = threadIdx.x;
  if (row >= MROWS) {
    Xb[(size_t)row * H_ + tid] = 0;
    Xb[(size_t)row * H_ + tid + 256] = 0;
    return;
  }
  float v0 = X[(size_t)row * H_ + tid];
  float v1 = X[(size_t)row * H_ + tid + 256];
  float sum = v0 + v1, sq = v0 * v0 + v1 * v1;
  __shared__ float sa[4], sb[4];
#pragma unroll
  for (int o = 1; o < 64; o <<= 1) {
    sum += __shfl_xor(sum, o);
    sq += __shfl_xor(sq, o);
  }
  int wv = tid >> 6, lane = tid & 63;
  if (lane == 0) { sa[wv] = sum; sb[wv] = sq; }
  __syncthreads();
  sum = sa[0] + sa[1] + sa[2] + sa[3];
  sq = sb[0] + sb[1] + sb[2] + sb[3];
  float mu = sum * (1.0f / H_);
  float var = sq * (1.0f / H_) - mu * mu;
  float rstd = rsqrtf(var + 1e-5f);
  float y0 = (v0 - mu) * rstd * g[tid] + be[tid];
  float y1 = (v1 - mu) * rstd * g[tid + 256] + be[tid + 256];
  X[(size_t)row * H_ + tid] = y0;
  X[(size_t)row * H_ + tid + 256] = y1;
  Xb[(size_t)row * H_ + tid] = f2bf(y0);
  Xb[(size_t)row * H_ + tid + 256] = f2bf(y1);
}

// ---------------- GEMM (global_load_lds staging) ----------------
// MODE 0: fused QKV, N=1536 -> scatter Q->(b,h,l,d), K->(b,h,l,d), V->(b,h,d,l)
// MODE 2: f32 o0[m,n] = resid[m,n] + acc + bias
// MODE 3: bf16 o0[m,n] = gelu(acc + bias), N=2048
template <int MODE>
__global__ __launch_bounds__(256) void gemm_kernel(const ushort_t* __restrict__ A,
                                                   const ushort_t* __restrict__ W,
                                                   const float* __restrict__ bias,
                                                   void* __restrict__ o0, void* __restrict__ o1,
                                                   void* __restrict__ o2,
                                                   const float* __restrict__ resid, int Ntiles,
                                                   int K) {
  __shared__ ushort_t As[4096];
  __shared__ ushort_t Bs[4096];
  const int tid = threadIdx.x;
  const int bx = blockIdx.x % Ntiles, by = blockIdx.x / Ntiles;
  const int m0 = by * 128, n0 = bx * 128;
  const int lane = tid & 63, wv = tid >> 6;
  const int wr = wv >> 1, wc = wv & 1;
  f32x4 acc[4][4] = {};

  const ushort_t* Ag0 = A + (size_t)(m0 + (tid >> 2)) * K + (tid & 3) * 8;
  const ushort_t* Ag1 = Ag0 + (size_t)64 * K;
  const ushort_t* Wg0 = W + (size_t)(n0 + (tid >> 2)) * K + (tid & 3) * 8;
  const ushort_t* Wg1 = Wg0 + (size_t)64 * K;
  ushort_t* lA0 = &As[wv * 512];
  ushort_t* lA1 = &As[2048 + wv * 512];
  ushort_t* lB0 = &Bs[wv * 512];
  ushort_t* lB1 = &Bs[2048 + wv * 512];

  for (int k0 = 0; k0 < K; k0 += 32) {
    gload16(Ag0 + k0, lA0);
    gload16(Ag1 + k0, lA1);
    gload16(Wg0 + k0, lB0);
    gload16(Wg1 + k0, lB1);
    __syncthreads();
    bf16x8 af[4], bfr[4];
#pragma unroll
    for (int mi = 0; mi < 4; mi++)
      af[mi] = *(const bf16x8*)&As[(wr * 64 + mi * 16 + (lane & 15)) * 32 + (lane >> 4) * 8];
#pragma unroll
    for (int ni = 0; ni < 4; ni++)
      bfr[ni] = *(const bf16x8*)&Bs[(wc * 64 + ni * 16 + (lane & 15)) * 32 + (lane >> 4) * 8];
#pragma unroll
    for (int mi = 0; mi < 4; mi++)
#pragma unroll
      for (int ni = 0; ni < 4; ni++)
        acc[mi][ni] = __builtin_amdgcn_mfma_f32_16x16x32_bf16(af[mi], bfr[ni], acc[mi][ni], 0, 0, 0);
    __syncthreads();
  }

#pragma unroll
  for (int mi = 0; mi < 4; mi++) {
#pragma unroll
    for (int ni = 0; ni < 4; ni++) {
#pragma unroll
      for (int r = 0; r < 4; r++) {
        int m = m0 + wr * 64 + mi * 16 + ((lane >> 4) << 2) + r;
        int n = n0 + wc * 64 + ni * 16 + (lane & 15);
        float val = acc[mi][ni][r] + bias[n];
        if (MODE == 0) {
          if (m < MROWS) {
            int b = m / L_;
            int l = m - b * L_;
            int which = n >> 9, nn = n & 511;
            int hh = nn >> 6, d = nn & 63;
            if (which == 0)
              ((ushort_t*)o0)[(((size_t)(b * NH_ + hh)) * LP_ + l) * DH_ + d] = f2bf(val);
            else if (which == 1)
              ((ushort_t*)o1)[(((size_t)(b * NH_ + hh)) * LP_ + l) * DH_ + d] = f2bf(val);
            else
              ((ushort_t*)o2)[(((size_t)(b * NH_ + hh)) * DH_ + d) * LP_ + l] = f2bf(val);
          }
        } else if (MODE == 2) {
          if (m < MROWS) {
            size_t off = (size_t)m * H_ + n;
            ((float*)o0)[off] = resid[off] + val;
          }
        } else {
          float ge = 0.5f * val * (1.0f + erff(val * 0.70710678f));
          ((ushort_t*)o0)[(size_t)m * HMLP + n] = f2bf(ge);
        }
      }
    }
  }
}

// ---------------- flash attention: 1 wave per 32 q-rows, swapped 32x32 MFMA ----------------
__global__ __launch_bounds__(256) void attn_kernel(const ushort_t* __restrict__ Qb,
                                                   const ushort_t* __restrict__ Kb,
                                                   const ushort_t* __restrict__ Vt,
                                                   ushort_t* __restrict__ Ob) {
  const int tid = threadIdx.x;
  const int lane = tid & 63, wv = tid >> 6;
  const int gw = blockIdx.x * 4 + wv;
  const int bh = gw / 34;
  const int tile = gw - bh * 34;
  const int b = bh >> 3, h = bh & 7;
  const int qbase = tile * 32;
  const int lq = lane & 31, hi = lane >> 5;

  const ushort_t* Qp = Qb + (size_t)bh * LP_ * DH_;
  const ushort_t* Kp = Kb + (size_t)bh * LP_ * DH_;
  const ushort_t* Vp = Vt + (size_t)bh * DH_ * LP_;

  // Q as B-operand: lane holds q = lq, d-elements = dc*16 + hi*8 + (0..7)
  bf16x8 qf[4];
#pragma unroll
  for (int dc = 0; dc < 4; dc++)
    qf[dc] = *(const bf16x8*)(Qp + (size_t)(qbase + lq) * DH_ + dc * 16 + hi * 8);

  f32x16 acc0 = {}, acc1 = {};  // C[d,q]: acc0 d 0..31, acc1 d 32..63
  float mrun = -1e30f, lrun = 0.f;

  int imax = qbase + 31;
  if (imax > L_ - 1) imax = L_ - 1;
  const int kend = (imax >= M_ + INFO_) ? L_ : ((imax < M_) ? M_ : (imax + 1));
  const int kend32 = (kend + 31) & ~31;
  const int i = qbase + lq;

  bf16x8 kf[4], vf[4], kfn[4], vfn[4];
#pragma unroll
  for (int dc = 0; dc < 4; dc++)
    kf[dc] = *(const bf16x8*)(Kp + (size_t)lq * DH_ + dc * 16 + hi * 8);
#pragma unroll
  for (int f = 0; f < 4; f++) {
    int dt = f >> 1, c = f & 1;
    vf[f] = *(const bf16x8*)(Vp + (size_t)(dt * 32 + lq) * LP_ + c * 16 + hi * 8);
  }

  for (int j0 = 0; j0 < kend32; j0 += 32) {
    const int jn = j0 + 32;
    const bool havenext = (jn < kend32);
    if (havenext) {
#pragma unroll
      for (int dc = 0; dc < 4; dc++)
        kfn[dc] = *(const bf16x8*)(Kp + (size_t)(jn + lq) * DH_ + dc * 16 + hi * 8);
#pragma unroll
      for (int f = 0; f < 4; f++) {
        int dt = f >> 1, c = f & 1;
        vfn[f] = *(const bf16x8*)(Vp + (size_t)(dt * 32 + lq) * LP_ + jn + c * 16 + hi * 8);
      }
    }
    // s[k,q]: lane holds q=lq, k-rows (r&3)+8*(r>>2)+4*hi
    f32x16 s = {};
#pragma unroll
    for (int dc = 0; dc < 4; dc++)
      s = __builtin_amdgcn_mfma_f32_32x32x16_bf16(kf[dc], qf[dc], s, 0, 0, 0);

    const bool needmask =
        (j0 + 31 >= L_) || (qbase < M_ + INFO_ && j0 + 31 >= M_ && j0 + 31 > qbase);
    float p[16];
    if (needmask) {
#pragma unroll
      for (int r = 0; r < 16; r++) {
        int j = j0 + (r & 3) + 8 * (r >> 2) + 4 * hi;
        bool ok = (j < L_) && ((j < M_) || (i >= M_ + INFO_) || (j <= i));
        p[r] = ok ? s[r] * 0.125f : -1e30f;
      }
    } else {
#pragma unroll
      for (int r = 0; r < 16; r++) p[r] = s[r] * 0.125f;
    }
    float mx = p[0];
#pragma unroll
    for (int r = 1; r < 16; r++) mx = fmaxf(mx, p[r]);
    {
      u32x2 t = __builtin_amdgcn_permlane32_swap(__builtin_bit_cast(unsigned, mx),
                                                 __builtin_bit_cast(unsigned, mx), false, false);
      mx = fmaxf(__builtin_bit_cast(float, t.x), __builtin_bit_cast(float, t.y));
    }
    const float mn = fmaxf(mrun, mx);
    const float fs = __expf(mrun - mn);
    mrun = mn;
    float psum = 0.f;
#pragma unroll
    for (int r = 0; r < 16; r++) {
      p[r] = __expf(p[r] - mn);
      psum += p[r];
    }
    {
      u32x2 t = __builtin_amdgcn_permlane32_swap(__builtin_bit_cast(unsigned, psum),
                                                 __builtin_bit_cast(unsigned, psum), false, false);
      psum = __builtin_bit_cast(float, t.x) + __builtin_bit_cast(float, t.y);
    }
    lrun = lrun * fs + psum;
    acc0 *= fs;
    acc1 *= fs;

    // P -> bf16 B-fragments via cvt_pk + permlane32_swap (T12)
    bf16x8 pf[2];
#pragma unroll
    for (int c = 0; c < 2; c++) {
      unsigned A01 = cvtpk_bf16(p[8 * c + 0], p[8 * c + 1]);
      unsigned A23 = cvtpk_bf16(p[8 * c + 2], p[8 * c + 3]);
      unsigned B45 = cvtpk_bf16(p[8 * c + 4], p[8 * c + 5]);
      unsigned B67 = cvtpk_bf16(p[8 * c + 6], p[8 * c + 7]);
      u32x2 r0 = __builtin_amdgcn_permlane32_swap(A01, B45, false, false);
      u32x2 r1 = __builtin_amdgcn_permlane32_swap(A23, B67, false, false);
      u32x4 w = {r0.x, r1.x, r0.y, r1.y};
      pf[c] = __builtin_bit_cast(bf16x8, w);
    }
    acc0 = __builtin_amdgcn_mfma_f32_32x32x16_bf16(vf[0], pf[0], acc0, 0, 0, 0);
    acc0 = __builtin_amdgcn_mfma_f32_32x32x16_bf16(vf[1], pf[1], acc0, 0, 0, 0);
    acc1 = __builtin_amdgcn_mfma_f32_32x32x16_bf16(vf[2], pf[0], acc1, 0, 0, 0);
    acc1 = __builtin_amdgcn_mfma_f32_32x32x16_bf16(vf[3], pf[1], acc1, 0, 0, 0);

    if (havenext) {
#pragma unroll
      for (int f = 0; f < 4; f++) {
        kf[f] = kfn[f];
        vf[f] = vfn[f];
      }
    }
  }

  if (i < L_) {
    const float inv = 1.0f / lrun;
    ushort_t* orow = Ob + ((size_t)(b * L_ + i)) * H_ + h * DH_;
#pragma unroll
    for (int dt = 0; dt < 2; dt++) {
#pragma unroll
      for (int q2 = 0; q2 < 4; q2++) {
        float a0 = (dt ? acc1[4 * q2 + 0] : acc0[4 * q2 + 0]) * inv;
        float a1 = (dt ? acc1[4 * q2 + 1] : acc0[4 * q2 + 1]) * inv;
        float a2 = (dt ? acc1[4 * q2 + 2] : acc0[4 * q2 + 2]) * inv;
        float a3 = (dt ? acc1[4 * q2 + 3] : acc0[4 * q2 + 3]) * inv;
        int dbase = dt * 32 + 8 * q2 + 4 * hi;
        *(unsigned*)(orow + dbase) = cvtpk_bf16(a0, a1);
        *(unsigned*)(orow + dbase + 2) = cvtpk_bf16(a2, a3);
      }
    }
  }
}

// ---------------- heads ----------------
__global__ __launch_bounds__(64) void logits_kernel(const float* __restrict__ X,
                                                    const float* __restrict__ Wp,
                                                    const float* __restrict__ bp,
                                                    float* __restrict__ out) {
  const int bt = blockIdx.x;
  const int b = bt / T_, t = bt - b * T_;
  const int lane = threadIdx.x;
  const float* xr = X + ((size_t)(b * L_ + M_ + 3 * t + 1)) * H_ + lane * 8;
  float x0[8];
#pragma unroll
  for (int ii = 0; ii < 8; ii++) x0[ii] = xr[ii];
#pragma unroll
  for (int a = 0; a < 4; a++) {
    const float* wr2 = Wp + (size_t)a * H_ + lane * 8;
    float p = 0.f;
#pragma unroll
    for (int ii = 0; ii < 8; ii++) p += x0[ii] * wr2[ii];
#pragma unroll
    for (int o = 1; o < 64; o <<= 1) p += __shfl_xor(p, o);
    if (lane == 0) out[(size_t)bt * 4 + a] = p + bp[a];
  }
}

__global__ __launch_bounds__(256) void memout_kernel(const float* __restrict__ X,
                                                     float* __restrict__ out) {
  int idx = blockIdx.x * 256 + threadIdx.x;
  if (idx < B_ * M_ * H_) {
    int b = idx >> 14;
    int rest = idx & 16383;
    int r = rest >> 9;
    int hh = rest & 511;
    out[idx] = X[((size_t)(b * L_ + M_ + INFO_ + r)) * H_ + hh];
  }
}

// ---------------- launcher ----------------
extern "C" void kernel_launch(void* const* d_in, const int* in_sizes, int n_in, void* d_out,
                              int out_size, void* d_ws, size_t ws_size, hipStream_t stream) {
  const float* returns = (const float*)d_in[0];
  const float* actions = (const float*)d_in[1];
  const float* t_table = (const float*)d_in[2];
  const float* s_table = (const float*)d_in[3];
  const float* Wr = (const float*)d_in[4];
  const float* br = (const float*)d_in[5];
  const float* Wa = (const float*)d_in[6];
  const float* ba = (const float*)d_in[7];
  const float* ln_e_g = (const float*)d_in[8];
  const float* ln_e_b = (const float*)d_in[9];
  const float* read_mem = (const float*)d_in[10];
  const float* mem_tok = (const float*)d_in[11];
  const float* Wq = (const float*)d_in[12];
  const float* bq = (const float*)d_in[13];
  const float* Wk = (const float*)d_in[14];
  const float* bk = (const float*)d_in[15];
  const float* Wv = (const float*)d_in[16];
  const float* bv = (const float*)d_in[17];
  const float* Wo = (const float*)d_in[18];
  const float* bo = (const float*)d_in[19];
  const float* W1 = (const float*)d_in[20];
  const float* b1 = (const float*)d_in[21];
  const float* W2 = (const float*)d_in[22];
  const float* b2 = (const float*)d_in[23];
  const float* g1 = (const float*)d_in[24];
  const float* be1 = (const float*)d_in[25];
  const float* g2 = (const float*)d_in[26];
  const float* be2 = (const float*)d_in[27];
  const float* Wp = (const float*)d_in[28];
  const float* bp = (const float*)d_in[29];
  const int* states = (const int*)d_in[30];
  const int* timestep = (const int*)d_in[31];

  char* ws = (char*)d_ws;
  size_t off = 0;
  auto alloc = [&](size_t bytes) -> char* {
    char* p = ws + off;
    off += (bytes + 255) & ~(size_t)255;
    return p;
  };
  float* X = (float*)alloc((size_t)MPAD * H_ * 4);
  ushort_t* Xb = (ushort_t*)alloc((size_t)MPAD * H_ * 2);
  ushort_t* Qb = (ushort_t*)alloc((size_t)B_ * NH_ * LP_ * DH_ * 2);
  ushort_t* Kb2 = (ushort_t*)alloc((size_t)B_ * NH_ * LP_ * DH_ * 2);
  ushort_t* Vt = (ushort_t*)alloc((size_t)B_ * NH_ * DH_ * LP_ * 2);
  ushort_t* Ob = (ushort_t*)alloc((size_t)MPAD * H_ * 2);
  ushort_t* Hm = (ushort_t*)alloc((size_t)MPAD * HMLP * 2);
  ushort_t* Wqkvb = (ushort_t*)alloc((size_t)4 * 1536 * 512 * 2);
  ushort_t* Wob = (ushort_t*)alloc((size_t)4 * 512 * 512 * 2);
  ushort_t* W1b = (ushort_t*)alloc((size_t)4 * 2048 * 512 * 2);
  ushort_t* W2b = (ushort_t*)alloc((size_t)4 * 512 * 2048 * 2);
  float* biascat = (float*)alloc((size_t)4 * 1536 * 4);

  zero_pads_kernel<<<128, 256, 0, stream>>>(Qb, Kb2, Vt, Ob);
  cvtqkv_kernel<<<4096, 256, 0, stream>>>(Wq, Wk, Wv, Wqkvb);
  biascat_kernel<<<8, 256, 0, stream>>>(bq, bk, bv, biascat);
  cvt_kernel<<<512, 256, 0, stream>>>(Wo, Wob, 4 * 512 * 512);
  cvt_kernel<<<512, 256, 0, stream>>>(W1, W1b, 4 * 2048 * 512);
  cvt_kernel<<<512, 256, 0, stream>>>(W2, W2b, 4 * 512 * 2048);

  embed_ln_kernel<<<MPAD, 256, 0, stream>>>(returns, actions, t_table, s_table, Wr, br, Wa,
                                            ba, ln_e_g, ln_e_b, read_mem, mem_tok, states,
                                            timestep, X, Xb);

  for (int nb = 0; nb < 4; ++nb) {
    const size_t wo512 = (size_t)nb * 512 * 512;
    const size_t woqkv = (size_t)nb * 1536 * 512;
    const size_t wo1 = (size_t)nb * 2048 * 512;
    gemm_kernel<0><<<68 * 12, 256, 0, stream>>>(Xb, Wqkvb + woqkv, biascat + nb * 1536, Qb,
                                                Kb2, Vt, nullptr, 12, 512);
    attn_kernel<<<544, 256, 0, stream>>>(Qb, Kb2, Vt, Ob);
    gemm_kernel<2><<<68 * 4, 256, 0, stream>>>(Ob, Wob + wo512, bo + nb * 512, X, nullptr,
                                               nullptr, X, 4, 512);
    ln_kernel<<<MPAD, 256, 0, stream>>>(X, g1 + nb * 512, be1 + nb * 512, Xb);
    gemm_kernel<3><<<68 * 16, 256, 0, stream>>>(Xb, W1b + wo1, b1 + nb * 2048, Hm, nullptr,
                                                nullptr, nullptr, 16, 512);
    gemm_kernel<2><<<68 * 4, 256, 0, stream>>>(Hm, W2b + wo1, b2 + nb * 512, X, nullptr,
                                               nullptr, X, 4, 2048);
    ln_kernel<<<MPAD, 256, 0, stream>>>(X, g2 + nb * 512, be2 + nb * 512, Xb);
  }

  logits_kernel<<<B_ * T_, 64, 0, stream>>>(X, Wp, bp, (float*)d_out);
  memout_kernel<<<512, 256, 0, stream>>>(X, (float*)d_out + (size_t)B_ * T_ * 4);
}

// Round 3
// 1116.559 us; speedup vs baseline: 1.3716x; 1.0629x over previous
//
#include <hip/hip_runtime.h>
#include <hip/hip_bf16.h>

typedef unsigned short ushort_t;
typedef __attribute__((ext_vector_type(8))) __bf16 bf16x8;
typedef __attribute__((ext_vector_type(4))) float f32x4;
typedef __attribute__((ext_vector_type(16))) float f32x16;
typedef __attribute__((ext_vector_type(2))) unsigned u32x2;
typedef __attribute__((ext_vector_type(4))) unsigned u32x4;

#define B_ 8
#define T_ 340
#define M_ 32
#define H_ 512
#define NH_ 8
#define DH_ 64
#define INFO_ 1020
#define L_ 1084
#define LP_ 1088
#define MROWS 8672
#define MPAD 8704
#define HMLP 2048

__device__ __forceinline__ ushort_t f2bf(float f) {
  unsigned u = __builtin_bit_cast(unsigned, f);
  unsigned r = (u + 0x7fffu + ((u >> 16) & 1u)) >> 16;
  return (ushort_t)r;
}

__device__ __forceinline__ unsigned cvtpk_bf16(float lo, float hi) {
  unsigned r;
  asm volatile("v_cvt_pk_bf16_f32 %0, %1, %2" : "=v"(r) : "v"(lo), "v"(hi));
  return r;
}

__device__ __forceinline__ void gload16(const ushort_t* g, ushort_t* l) {
  __builtin_amdgcn_global_load_lds((const __attribute__((address_space(1))) unsigned*)g,
                                   (__attribute__((address_space(3))) unsigned*)l, 16, 0, 0);
}

// ---------------- zero pads (Q/K l-pads, Vt l-pads, Ob row-pads) ----------------
__global__ __launch_bounds__(256) void zero_pads_kernel(ushort_t* Qb, ushort_t* Kb,
                                                        ushort_t* Vt, ushort_t* Ob) {
  int idx = blockIdx.x * 256 + threadIdx.x;
  if (idx < 16384) {
    int bh = idx >> 8;
    int rest = idx & 255;
    int l = L_ + (rest >> 6);
    int d = rest & 63;
    size_t o = ((size_t)bh * LP_ + l) * DH_ + d;
    Qb[o] = 0;
    Kb[o] = 0;
    Vt[((size_t)bh * DH_ + d) * LP_ + l] = 0;
  } else if (idx < 32768) {
    int j = idx - 16384;
    Ob[(size_t)MROWS * H_ + j] = 0;
  }
}

// ---------------- f32 -> bf16 convert ----------------
__global__ __launch_bounds__(256) void cvt_kernel(const float* __restrict__ src,
                                                  ushort_t* __restrict__ dst, int n) {
  int i = blockIdx.x * 256 + threadIdx.x;
  int stride = gridDim.x * 256;
  for (; i < n; i += stride) dst[i] = f2bf(src[i]);
}

// ---------------- Wq/Wk/Wv -> concatenated bf16 [nb][1536][512] ----------------
__global__ __launch_bounds__(256) void cvtqkv_kernel(const float* __restrict__ q,
                                                     const float* __restrict__ k,
                                                     const float* __restrict__ v,
                                                     ushort_t* __restrict__ dst) {
  int i = blockIdx.x * 256 + threadIdx.x;
  if (i >= 4 * 512 * 512) return;
  int nb = i >> 18;
  int rem = i & 262143;
  size_t base = (size_t)nb * 786432 + rem;
  dst[base] = f2bf(q[i]);
  dst[base + 262144] = f2bf(k[i]);
  dst[base + 524288] = f2bf(v[i]);
}

__global__ __launch_bounds__(256) void biascat_kernel(const float* __restrict__ bq,
                                                      const float* __restrict__ bk,
                                                      const float* __restrict__ bv,
                                                      float* __restrict__ dst) {
  int i = blockIdx.x * 256 + threadIdx.x;
  if (i < 2048) {
    int nb = i >> 9, r = i & 511;
    float* d = dst + nb * 1536;
    d[r] = bq[i];
    d[512 + r] = bk[i];
    d[1024 + r] = bv[i];
  }
}

// ---------------- embedding + initial LN ----------------
__global__ __launch_bounds__(256) void embed_ln_kernel(
    const float* __restrict__ returns, const float* __restrict__ actions,
    const float* __restrict__ t_table, const float* __restrict__ s_table,
    const float* __restrict__ Wr, const float* __restrict__ br,
    const float* __restrict__ Wa, const float* __restrict__ ba,
    const float* __restrict__ g, const float* __restrict__ be,
    const float* __restrict__ read_mem, const float* __restrict__ mem_tok,
    const int* __restrict__ states, const int* __restrict__ timestep,
    float* __restrict__ X, ushort_t* __restrict__ Xb) {
  const int row = blockIdx.x;
  const int tid = threadIdx.x;
  if (row >= MROWS) {
    Xb[(size_t)row * H_ + tid] = 0;
    Xb[(size_t)row * H_ + tid + 256] = 0;
    return;
  }
  const int b = row / L_, l = row - b * L_;
  float v[2];
#pragma unroll
  for (int s2 = 0; s2 < 2; s2++) {
    int hh = tid + s2 * 256;
    float val;
    if (l < M_) {
      val = read_mem[(size_t)l * H_ + hh];
    } else if (l >= M_ + INFO_) {
      val = mem_tok[(size_t)(l - M_ - INFO_) * H_ + hh];
    } else {
      int ii = l - M_;
      int t = ii / 3, c = ii - t * 3;
      int bt = b * T_ + t;
      if (c == 1) {
        val = s_table[(size_t)states[bt] * H_ + hh];
      } else {
        float te = t_table[(size_t)timestep[bt] * H_ + hh];
        val = (c == 0 ? returns[bt] * Wr[hh] + br[hh] : actions[bt] * Wa[hh] + ba[hh]) + te;
      }
    }
    v[s2] = val;
  }
  float sum = v[0] + v[1], sq = v[0] * v[0] + v[1] * v[1];
  __shared__ float sa[4], sb[4];
#pragma unroll
  for (int o = 1; o < 64; o <<= 1) {
    sum += __shfl_xor(sum, o);
    sq += __shfl_xor(sq, o);
  }
  int wv = tid >> 6, lane = tid & 63;
  if (lane == 0) { sa[wv] = sum; sb[wv] = sq; }
  __syncthreads();
  sum = sa[0] + sa[1] + sa[2] + sa[3];
  sq = sb[0] + sb[1] + sb[2] + sb[3];
  float mu = sum * (1.0f / H_);
  float var = sq * (1.0f / H_) - mu * mu;
  float rstd = rsqrtf(var + 1e-5f);
#pragma unroll
  for (int s2 = 0; s2 < 2; s2++) {
    int hh = tid + s2 * 256;
    float y = (v[s2] - mu) * rstd * g[hh] + be[hh];
    X[(size_t)row * H_ + hh] = y;
    Xb[(size_t)row * H_ + hh] = f2bf(y);
  }
}

// ---------------- LN over residual stream (in place) ----------------
__global__ __launch_bounds__(256) void ln_kernel(float* __restrict__ X,
                                                 const float* __restrict__ g,
                                                 const float* __restrict__ be,
                                                 ushort_t* __restrict__ Xb) {
  const int row = blockIdx.x;
  const int tid = threadIdx.x;
  if (row >= MROWS) {
    Xb[(size_t)row * H_ + tid] = 0;
    Xb[(size_t)row * H_ + tid + 256] = 0;
    return;
  }
  float v0 = X[(size_t)row * H_ + tid];
  float v1 = X[(size_t)row * H_ + tid + 256];
  float sum = v0 + v1, sq = v0 * v0 + v1 * v1;
  __shared__ float sa[4], sb[4];
#pragma unroll
  for (int o = 1; o < 64; o <<= 1) {
    sum += __shfl_xor(sum, o);
    sq += __shfl_xor(sq, o);
  }
  int wv = tid >> 6, lane = tid & 63;
  if (lane == 0) { sa[wv] = sum; sb[wv] = sq; }
  __syncthreads();
  sum = sa[0] + sa[1] + sa[2] + sa[3];
  sq = sb[0] + sb[1] + sb[2] + sb[3];
  float mu = sum * (1.0f / H_);
  float var = sq * (1.0f / H_) - mu * mu;
  float rstd = rsqrtf(var + 1e-5f);
  float y0 = (v0 - mu) * rstd * g[tid] + be[tid];
  float y1 = (v1 - mu) * rstd * g[tid + 256] + be[tid + 256];
  X[(size_t)row * H_ + tid] = y0;
  X[(size_t)row * H_ + tid + 256] = y1;
  Xb[(size_t)row * H_ + tid] = f2bf(y0);
  Xb[(size_t)row * H_ + tid + 256] = f2bf(y1);
}

// ---------------- GEMM: BK=64, double-buffered LDS, counted vmcnt, XOR swizzle ----------
// MODE 0: fused QKV, N=1536 -> scatter Q->(b,h,l,d), K->(b,h,l,d), V->(b,h,d,l)
// MODE 2: f32 o0[m,n] = resid[m,n] + acc + bias
// MODE 3: bf16 o0[m,n] = gelu(acc + bias), N=2048
template <int MODE>
__global__ __launch_bounds__(256, 2) void gemm_kernel(const ushort_t* __restrict__ A,
                                                      const ushort_t* __restrict__ W,
                                                      const float* __restrict__ bias,
                                                      void* __restrict__ o0,
                                                      void* __restrict__ o1,
                                                      void* __restrict__ o2,
                                                      const float* __restrict__ resid,
                                                      int Ntiles, int K) {
  // [2 bufs][128 rows][64 cols] bf16 each; rows are 128 B (8 x 16B slots)
  __shared__ ushort_t As[2][8192];
  __shared__ ushort_t Bs[2][8192];
  const int tid = threadIdx.x;
  const int bx = blockIdx.x % Ntiles, by = blockIdx.x / Ntiles;
  const int m0 = by * 128, n0 = bx * 128;
  const int lane = tid & 63, wv = tid >> 6;
  const int wr = wv >> 1, wc = wv & 1;
  f32x4 acc[4][4] = {};

  // staging: wave wv covers rows wv*32..wv*32+31; gload g covers 8 rows (1 KB).
  // linear LDS dest slot = lane&7; global k-chunk pre-swizzled: kg = (lane&7) ^ (row&7)
  const int srow = lane >> 3;        // row within 8-row group == row&7
  const int kg = (lane & 7) ^ srow;  // swizzled 16B k-chunk index
  const ushort_t* Asrc[4];
  const ushort_t* Bsrc[4];
#pragma unroll
  for (int g2 = 0; g2 < 4; g2++) {
    int row = wv * 32 + g2 * 8 + srow;
    Asrc[g2] = A + (size_t)(m0 + row) * K + kg * 8;
    Bsrc[g2] = W + (size_t)(n0 + row) * K + kg * 8;
  }
  ushort_t* ldsA[2] = {&As[0][wv * 2048], &As[1][wv * 2048]};
  ushort_t* ldsB[2] = {&Bs[0][wv * 2048], &Bs[1][wv * 2048]};

  const int NT = K >> 6;

  // prologue: stage tile 0 into buf 0 (8 gloads/wave)
#pragma unroll
  for (int g2 = 0; g2 < 4; g2++) {
    gload16(Asrc[g2], ldsA[0] + g2 * 512);
    gload16(Bsrc[g2], ldsB[0] + g2 * 512);
  }

  // read-side swizzled slots (uniform across mi/ni since rows stride 16)
  const int q = lane >> 4, lr = lane & 15;
  const int s0 = q ^ (lr & 7);
  const int s1 = (4 + q) ^ (lr & 7);

  auto compute_tile = [&](int cur) {
    bf16x8 af[4][2], bfr[4][2];
#pragma unroll
    for (int mi = 0; mi < 4; mi++) {
      const ushort_t* rp = &As[cur][(wr * 64 + mi * 16 + lr) * 64];
      af[mi][0] = *(const bf16x8*)(rp + s0 * 8);
      af[mi][1] = *(const bf16x8*)(rp + s1 * 8);
    }
#pragma unroll
    for (int ni = 0; ni < 4; ni++) {
      const ushort_t* rp = &Bs[cur][(wc * 64 + ni * 16 + lr) * 64];
      bfr[ni][0] = *(const bf16x8*)(rp + s0 * 8);
      bfr[ni][1] = *(const bf16x8*)(rp + s1 * 8);
    }
#pragma unroll
    for (int kc = 0; kc < 2; kc++)
#pragma unroll
      for (int mi = 0; mi < 4; mi++)
#pragma unroll
        for (int ni = 0; ni < 4; ni++)
          acc[mi][ni] =
              __builtin_amdgcn_mfma_f32_16x16x32_bf16(af[mi][kc], bfr[ni][kc], acc[mi][ni], 0, 0, 0);
  };

  for (int kt = 0; kt < NT - 1; kt++) {
    const int cur = kt & 1, nxt = cur ^ 1;
    const int k0n = (kt + 1) << 6;
#pragma unroll
    for (int g2 = 0; g2 < 4; g2++) {
      gload16(Asrc[g2] + k0n, ldsA[nxt] + g2 * 512);
      gload16(Bsrc[g2] + k0n, ldsB[nxt] + g2 * 512);
    }
    // wait only for CURRENT tile's 8 loads; next tile's 8 stay in flight (T4)
    asm volatile("s_waitcnt vmcnt(8)" ::: "memory");
    __builtin_amdgcn_s_barrier();
    asm volatile("" ::: "memory");
    compute_tile(cur);
    asm volatile("" ::: "memory");
    __builtin_amdgcn_s_barrier();  // protect buf[nxt] write-after-read
  }
  {
    asm volatile("s_waitcnt vmcnt(0)" ::: "memory");
    __builtin_amdgcn_s_barrier();
    asm volatile("" ::: "memory");
    compute_tile((NT - 1) & 1);
  }

#pragma unroll
  for (int mi = 0; mi < 4; mi++) {
#pragma unroll
    for (int ni = 0; ni < 4; ni++) {
#pragma unroll
      for (int r = 0; r < 4; r++) {
        int m = m0 + wr * 64 + mi * 16 + ((lane >> 4) << 2) + r;
        int n = n0 + wc * 64 + ni * 16 + (lane & 15);
        float val = acc[mi][ni][r] + bias[n];
        if (MODE == 0) {
          if (m < MROWS) {
            int b = m / L_;
            int l = m - b * L_;
            int which = n >> 9, nn = n & 511;
            int hh = nn >> 6, d = nn & 63;
            if (which == 0)
              ((ushort_t*)o0)[(((size_t)(b * NH_ + hh)) * LP_ + l) * DH_ + d] = f2bf(val);
            else if (which == 1)
              ((ushort_t*)o1)[(((size_t)(b * NH_ + hh)) * LP_ + l) * DH_ + d] = f2bf(val);
            else
              ((ushort_t*)o2)[(((size_t)(b * NH_ + hh)) * DH_ + d) * LP_ + l] = f2bf(val);
          }
        } else if (MODE == 2) {
          if (m < MROWS) {
            size_t off = (size_t)m * H_ + n;
            ((float*)o0)[off] = resid[off] + val;
          }
        } else {
          float ge = 0.5f * val * (1.0f + erff(val * 0.70710678f));
          ((ushort_t*)o0)[(size_t)m * HMLP + n] = f2bf(ge);
        }
      }
    }
  }
}

// ---------------- flash attention: 1 wave per 32 q-rows, swapped 32x32 MFMA ----------------
__global__ __launch_bounds__(256) void attn_kernel(const ushort_t* __restrict__ Qb,
                                                   const ushort_t* __restrict__ Kb,
                                                   const ushort_t* __restrict__ Vt,
                                                   ushort_t* __restrict__ Ob) {
  const int tid = threadIdx.x;
  const int lane = tid & 63, wv = tid >> 6;
  const int gw = blockIdx.x * 4 + wv;
  const int bh = gw / 34;
  const int tile = gw - bh * 34;
  const int b = bh >> 3, h = bh & 7;
  const int qbase = tile * 32;
  const int lq = lane & 31, hi = lane >> 5;

  const ushort_t* Qp = Qb + (size_t)bh * LP_ * DH_;
  const ushort_t* Kp = Kb + (size_t)bh * LP_ * DH_;
  const ushort_t* Vp = Vt + (size_t)bh * DH_ * LP_;

  bf16x8 qf[4];
#pragma unroll
  for (int dc = 0; dc < 4; dc++)
    qf[dc] = *(const bf16x8*)(Qp + (size_t)(qbase + lq) * DH_ + dc * 16 + hi * 8);

  f32x16 acc0 = {}, acc1 = {};
  float mrun = -1e30f, lrun = 0.f;

  int imax = qbase + 31;
  if (imax > L_ - 1) imax = L_ - 1;
  const int kend = (imax >= M_ + INFO_) ? L_ : ((imax < M_) ? M_ : (imax + 1));
  const int kend32 = (kend + 31) & ~31;
  const int i = qbase + lq;

  bf16x8 kf[4], vf[4], kfn[4], vfn[4];
#pragma unroll
  for (int dc = 0; dc < 4; dc++)
    kf[dc] = *(const bf16x8*)(Kp + (size_t)lq * DH_ + dc * 16 + hi * 8);
#pragma unroll
  for (int f = 0; f < 4; f++) {
    int dt = f >> 1, c = f & 1;
    vf[f] = *(const bf16x8*)(Vp + (size_t)(dt * 32 + lq) * LP_ + c * 16 + hi * 8);
  }

  for (int j0 = 0; j0 < kend32; j0 += 32) {
    const int jn = j0 + 32;
    const bool havenext = (jn < kend32);
    if (havenext) {
#pragma unroll
      for (int dc = 0; dc < 4; dc++)
        kfn[dc] = *(const bf16x8*)(Kp + (size_t)(jn + lq) * DH_ + dc * 16 + hi * 8);
#pragma unroll
      for (int f = 0; f < 4; f++) {
        int dt = f >> 1, c = f & 1;
        vfn[f] = *(const bf16x8*)(Vp + (size_t)(dt * 32 + lq) * LP_ + jn + c * 16 + hi * 8);
      }
    }
    f32x16 s = {};
#pragma unroll
    for (int dc = 0; dc < 4; dc++)
      s = __builtin_amdgcn_mfma_f32_32x32x16_bf16(kf[dc], qf[dc], s, 0, 0, 0);

    const bool needmask =
        (j0 + 31 >= L_) || (qbase < M_ + INFO_ && j0 + 31 >= M_ && j0 + 31 > qbase);
    float p[16];
    if (needmask) {
#pragma unroll
      for (int r = 0; r < 16; r++) {
        int j = j0 + (r & 3) + 8 * (r >> 2) + 4 * hi;
        bool ok = (j < L_) && ((j < M_) || (i >= M_ + INFO_) || (j <= i));
        p[r] = ok ? s[r] * 0.125f : -1e30f;
      }
    } else {
#pragma unroll
      for (int r = 0; r < 16; r++) p[r] = s[r] * 0.125f;
    }
    float mx = p[0];
#pragma unroll
    for (int r = 1; r < 16; r++) mx = fmaxf(mx, p[r]);
    {
      u32x2 t = __builtin_amdgcn_permlane32_swap(__builtin_bit_cast(unsigned, mx),
                                                 __builtin_bit_cast(unsigned, mx), false, false);
      mx = fmaxf(__builtin_bit_cast(float, t.x), __builtin_bit_cast(float, t.y));
    }
    const float mn = fmaxf(mrun, mx);
    const float fs = __expf(mrun - mn);
    mrun = mn;
    float psum = 0.f;
#pragma unroll
    for (int r = 0; r < 16; r++) {
      p[r] = __expf(p[r] - mn);
      psum += p[r];
    }
    {
      u32x2 t = __builtin_amdgcn_permlane32_swap(__builtin_bit_cast(unsigned, psum),
                                                 __builtin_bit_cast(unsigned, psum), false, false);
      psum = __builtin_bit_cast(float, t.x) + __builtin_bit_cast(float, t.y);
    }
    lrun = lrun * fs + psum;
    acc0 *= fs;
    acc1 *= fs;

    bf16x8 pf[2];
#pragma unroll
    for (int c = 0; c < 2; c++) {
      unsigned A01 = cvtpk_bf16(p[8 * c + 0], p[8 * c + 1]);
      unsigned A23 = cvtpk_bf16(p[8 * c + 2], p[8 * c + 3]);
      unsigned B45 = cvtpk_bf16(p[8 * c + 4], p[8 * c + 5]);
      unsigned B67 = cvtpk_bf16(p[8 * c + 6], p[8 * c + 7]);
      u32x2 r0 = __builtin_amdgcn_permlane32_swap(A01, B45, false, false);
      u32x2 r1 = __builtin_amdgcn_permlane32_swap(A23, B67, false, false);
      u32x4 w = {r0.x, r1.x, r0.y, r1.y};
      pf[c] = __builtin_bit_cast(bf16x8, w);
    }
    acc0 = __builtin_amdgcn_mfma_f32_32x32x16_bf16(vf[0], pf[0], acc0, 0, 0, 0);
    acc0 = __builtin_amdgcn_mfma_f32_32x32x16_bf16(vf[1], pf[1], acc0, 0, 0, 0);
    acc1 = __builtin_amdgcn_mfma_f32_32x32x16_bf16(vf[2], pf[0], acc1, 0, 0, 0);
    acc1 = __builtin_amdgcn_mfma_f32_32x32x16_bf16(vf[3], pf[1], acc1, 0, 0, 0);

    if (havenext) {
#pragma unroll
      for (int f = 0; f < 4; f++) {
        kf[f] = kfn[f];
        vf[f] = vfn[f];
      }
    }
  }

  if (i < L_) {
    const float inv = 1.0f / lrun;
    ushort_t* orow = Ob + ((size_t)(b * L_ + i)) * H_ + h * DH_;
#pragma unroll
    for (int dt = 0; dt < 2; dt++) {
#pragma unroll
      for (int q2 = 0; q2 < 4; q2++) {
        float a0 = (dt ? acc1[4 * q2 + 0] : acc0[4 * q2 + 0]) * inv;
        float a1 = (dt ? acc1[4 * q2 + 1] : acc0[4 * q2 + 1]) * inv;
        float a2 = (dt ? acc1[4 * q2 + 2] : acc0[4 * q2 + 2]) * inv;
        float a3 = (dt ? acc1[4 * q2 + 3] : acc0[4 * q2 + 3]) * inv;
        int dbase = dt * 32 + 8 * q2 + 4 * hi;
        *(unsigned*)(orow + dbase) = cvtpk_bf16(a0, a1);
        *(unsigned*)(orow + dbase + 2) = cvtpk_bf16(a2, a3);
      }
    }
  }
}

// ---------------- heads ----------------
__global__ __launch_bounds__(64) void logits_kernel(const float* __restrict__ X,
                                                    const float* __restrict__ Wp,
                                                    const float* __restrict__ bp,
                                                    float* __restrict__ out) {
  const int bt = blockIdx.x;
  const int b = bt / T_, t = bt - b * T_;
  const int lane = threadIdx.x;
  const float* xr = X + ((size_t)(b * L_ + M_ + 3 * t + 1)) * H_ + lane * 8;
  float x0[8];
#pragma unroll
  for (int ii = 0; ii < 8; ii++) x0[ii] = xr[ii];
#pragma unroll
  for (int a = 0; a < 4; a++) {
    const float* wr2 = Wp + (size_t)a * H_ + lane * 8;
    float p = 0.f;
#pragma unroll
    for (int ii = 0; ii < 8; ii++) p += x0[ii] * wr2[ii];
#pragma unroll
    for (int o = 1; o < 64; o <<= 1) p += __shfl_xor(p, o);
    if (lane == 0) out[(size_t)bt * 4 + a] = p + bp[a];
  }
}

__global__ __launch_bounds__(256) void memout_kernel(const float* __restrict__ X,
                                                     float* __restrict__ out) {
  int idx = blockIdx.x * 256 + threadIdx.x;
  if (idx < B_ * M_ * H_) {
    int b = idx >> 14;
    int rest = idx & 16383;
    int r = rest >> 9;
    int hh = rest & 511;
    out[idx] = X[((size_t)(b * L_ + M_ + INFO_ + r)) * H_ + hh];
  }
}

// ---------------- launcher ----------------
extern "C" void kernel_launch(void* const* d_in, const int* in_sizes, int n_in, void* d_out,
                              int out_size, void* d_ws, size_t ws_size, hipStream_t stream) {
  const float* returns = (const float*)d_in[0];
  const float* actions = (const float*)d_in[1];
  const float* t_table = (const float*)d_in[2];
  const float* s_table = (const float*)d_in[3];
  const float* Wr = (const float*)d_in[4];
  const float* br = (const float*)d_in[5];
  const float* Wa = (const float*)d_in[6];
  const float* ba = (const float*)d_in[7];
  const float* ln_e_g = (const float*)d_in[8];
  const float* ln_e_b = (const float*)d_in[9];
  const float* read_mem = (const float*)d_in[10];
  const float* mem_tok = (const float*)d_in[11];
  const float* Wq = (const float*)d_in[12];
  const float* bq = (const float*)d_in[13];
  const float* Wk = (const float*)d_in[14];
  const float* bk = (const float*)d_in[15];
  const float* Wv = (const float*)d_in[16];
  const float* bv = (const float*)d_in[17];
  const float* Wo = (const float*)d_in[18];
  const float* bo = (const float*)d_in[19];
  const float* W1 = (const float*)d_in[20];
  const float* b1 = (const float*)d_in[21];
  const float* W2 = (const float*)d_in[22];
  const float* b2 = (const float*)d_in[23];
  const float* g1 = (const float*)d_in[24];
  const float* be1 = (const float*)d_in[25];
  const float* g2 = (const float*)d_in[26];
  const float* be2 = (const float*)d_in[27];
  const float* Wp = (const float*)d_in[28];
  const float* bp = (const float*)d_in[29];
  const int* states = (const int*)d_in[30];
  const int* timestep = (const int*)d_in[31];

  char* ws = (char*)d_ws;
  size_t off = 0;
  auto alloc = [&](size_t bytes) -> char* {
    char* p = ws + off;
    off += (bytes + 255) & ~(size_t)255;
    return p;
  };
  float* X = (float*)alloc((size_t)MPAD * H_ * 4);
  ushort_t* Xb = (ushort_t*)alloc((size_t)MPAD * H_ * 2);
  ushort_t* Qb = (ushort_t*)alloc((size_t)B_ * NH_ * LP_ * DH_ * 2);
  ushort_t* Kb2 = (ushort_t*)alloc((size_t)B_ * NH_ * LP_ * DH_ * 2);
  ushort_t* Vt = (ushort_t*)alloc((size_t)B_ * NH_ * DH_ * LP_ * 2);
  ushort_t* Ob = (ushort_t*)alloc((size_t)MPAD * H_ * 2);
  ushort_t* Hm = (ushort_t*)alloc((size_t)MPAD * HMLP * 2);
  ushort_t* Wqkvb = (ushort_t*)alloc((size_t)4 * 1536 * 512 * 2);
  ushort_t* Wob = (ushort_t*)alloc((size_t)4 * 512 * 512 * 2);
  ushort_t* W1b = (ushort_t*)alloc((size_t)4 * 2048 * 512 * 2);
  ushort_t* W2b = (ushort_t*)alloc((size_t)4 * 512 * 2048 * 2);
  float* biascat = (float*)alloc((size_t)4 * 1536 * 4);

  zero_pads_kernel<<<128, 256, 0, stream>>>(Qb, Kb2, Vt, Ob);
  cvtqkv_kernel<<<4096, 256, 0, stream>>>(Wq, Wk, Wv, Wqkvb);
  biascat_kernel<<<8, 256, 0, stream>>>(bq, bk, bv, biascat);
  cvt_kernel<<<512, 256, 0, stream>>>(Wo, Wob, 4 * 512 * 512);
  cvt_kernel<<<512, 256, 0, stream>>>(W1, W1b, 4 * 2048 * 512);
  cvt_kernel<<<512, 256, 0, stream>>>(W2, W2b, 4 * 512 * 2048);

  embed_ln_kernel<<<MPAD, 256, 0, stream>>>(returns, actions, t_table, s_table, Wr, br, Wa,
                                            ba, ln_e_g, ln_e_b, read_mem, mem_tok, states,
                                            timestep, X, Xb);

  for (int nb = 0; nb < 4; ++nb) {
    const size_t wo512 = (size_t)nb * 512 * 512;
    const size_t woqkv = (size_t)nb * 1536 * 512;
    const size_t wo1 = (size_t)nb * 2048 * 512;
    gemm_kernel<0><<<68 * 12, 256, 0, stream>>>(Xb, Wqkvb + woqkv, biascat + nb * 1536, Qb,
                                                Kb2, Vt, nullptr, 12, 512);
    attn_kernel<<<544, 256, 0, stream>>>(Qb, Kb2, Vt, Ob);
    gemm_kernel<2><<<68 * 4, 256, 0, stream>>>(Ob, Wob + wo512, bo + nb * 512, X, nullptr,
                                               nullptr, X, 4, 512);
    ln_kernel<<<MPAD, 256, 0, stream>>>(X, g1 + nb * 512, be1 + nb * 512, Xb);
    gemm_kernel<3><<<68 * 16, 256, 0, stream>>>(Xb, W1b + wo1, b1 + nb * 2048, Hm, nullptr,
                                                nullptr, nullptr, 16, 512);
    gemm_kernel<2><<<68 * 4, 256, 0, stream>>>(Hm, W2b + wo1, b2 + nb * 512, X, nullptr,
                                               nullptr, X, 4, 2048);
    ln_kernel<<<MPAD, 256, 0, stream>>>(X, g2 + nb * 512, be2 + nb * 512, Xb);
  }

  logits_kernel<<<B_ * T_, 64, 0, stream>>>(X, Wp, bp, (float*)d_out);
  memout_kernel<<<512, 256, 0, stream>>>(X, (float*)d_out + (size_t)B_ * T_ * 4);
}